// Round 1
// baseline (135.103 us; speedup 1.0000x reference)
//
#include <hip/hip_runtime.h>

#define B_N   1024
#define F_DIMC 768
#define M_DIM  512
#define C_N    100

// ---------------------------------------------------------------------------
// Kernel 0: per-class index lists (deterministic: ascending sample order)
// ---------------------------------------------------------------------------
__global__ __launch_bounds__(128) void build_index_kernel(
    const int* __restrict__ labels, int* __restrict__ counts,
    int* __restrict__ idx) {
  int c = threadIdx.x;
  if (c >= C_N) return;
  int cnt = 0;
  int* my = idx + c * B_N;
  for (int i = 0; i < B_N; ++i) {
    if (labels[i] == c) { my[cnt] = i; ++cnt; }
  }
  counts[c] = cnt;
}

// ---------------------------------------------------------------------------
// Kernel 1: feat = relu(X @ W)   [1024,768] x [768,512] -> [1024,512] fp32
// 32x32 tile, BK=16, 128 threads, 2x4 acc per thread, grid 512 blocks.
// ---------------------------------------------------------------------------
__global__ __launch_bounds__(128) void feat_gemm_kernel(
    const float* __restrict__ X, const float* __restrict__ W,
    float* __restrict__ feat) {
  __shared__ float As[16][36];  // A^T tile (k-major), padded: 2-way max on write
  __shared__ float Bs[16][32];

  const int bm = (int)(blockIdx.x >> 4) * 32;  // 32 row blocks
  const int bn = (int)(blockIdx.x & 15) * 32;  // 16 col blocks
  const int t  = threadIdx.x;
  const int tx = t & 7;    // col group (x4)
  const int ty = t >> 3;   // row group (x2)

  const int arow = t >> 2, akq = (t & 3) * 4;   // A tile load map
  const int bkr  = t >> 3, bnq = (t & 7) * 4;   // B tile load map

  float acc[2][4] = {};

  for (int k0 = 0; k0 < F_DIMC; k0 += 16) {
    float4 a = *(const float4*)&X[(size_t)(bm + arow) * F_DIMC + k0 + akq];
    As[akq + 0][arow] = a.x;
    As[akq + 1][arow] = a.y;
    As[akq + 2][arow] = a.z;
    As[akq + 3][arow] = a.w;
    *(float4*)&Bs[bkr][bnq] =
        *(const float4*)&W[(size_t)(k0 + bkr) * M_DIM + bn + bnq];
    __syncthreads();
#pragma unroll
    for (int kk = 0; kk < 16; ++kk) {
      float2 av = *(const float2*)&As[kk][ty * 2];
      float4 bv = *(const float4*)&Bs[kk][tx * 4];
      acc[0][0] += av.x * bv.x;
      acc[0][1] += av.x * bv.y;
      acc[0][2] += av.x * bv.z;
      acc[0][3] += av.x * bv.w;
      acc[1][0] += av.y * bv.x;
      acc[1][1] += av.y * bv.y;
      acc[1][2] += av.y * bv.z;
      acc[1][3] += av.y * bv.w;
    }
    __syncthreads();
  }

#pragma unroll
  for (int j = 0; j < 2; ++j) {
    float4 o;
    o.x = fmaxf(acc[j][0], 0.0f);
    o.y = fmaxf(acc[j][1], 0.0f);
    o.z = fmaxf(acc[j][2], 0.0f);
    o.w = fmaxf(acc[j][3], 0.0f);
    *(float4*)&feat[(size_t)(bm + ty * 2 + j) * M_DIM + bn + tx * 4] = o;
  }
}

// ---------------------------------------------------------------------------
// Kernel 2: phi[c] = sum_{i in class c} feat_i^T feat_i
// grid = (64 tiles of 64x64, C classes); 256 threads; 4x4 acc per thread.
// Stages up to 16 samples' row-slices (A: cols tm..tm+64, B: cols tn..tn+64).
// ---------------------------------------------------------------------------
__global__ __launch_bounds__(256) void phi_kernel(
    const float* __restrict__ feat, const int* __restrict__ counts,
    const int* __restrict__ idx, float* __restrict__ phi) {
  const int c    = blockIdx.y;
  const int tile = blockIdx.x;          // 0..63
  const int tm   = (tile >> 3) * 64;
  const int tn   = (tile & 7) * 64;
  const int n    = counts[c];
  const int* __restrict__ id = idx + c * B_N;

  __shared__ float As[16][64];
  __shared__ float Bs[16][64];

  const int t  = threadIdx.x;
  const int tx = t & 15;   // col group (x4)
  const int ty = t >> 4;   // row group (x4)

  float acc[4][4] = {};

  for (int s0 = 0; s0 < n; s0 += 16) {
    const int chunk  = min(16, n - s0);
    const int nslots = chunk * 32;      // float4 slots this chunk
    for (int v = t; v < nslots; v += 256) {
      const int sl   = v >> 5;
      const int part = v & 31;
      const int i    = id[s0 + sl];
      if (part < 16)
        *(float4*)&As[sl][part * 4] =
            *(const float4*)&feat[(size_t)i * M_DIM + tm + part * 4];
      else
        *(float4*)&Bs[sl][(part - 16) * 4] =
            *(const float4*)&feat[(size_t)i * M_DIM + tn + (part - 16) * 4];
    }
    __syncthreads();
    for (int sl = 0; sl < chunk; ++sl) {
      float4 a  = *(const float4*)&As[sl][ty * 4];
      float4 b4 = *(const float4*)&Bs[sl][tx * 4];
      float av[4] = {a.x, a.y, a.z, a.w};
      float bv[4] = {b4.x, b4.y, b4.z, b4.w};
#pragma unroll
      for (int j = 0; j < 4; ++j)
#pragma unroll
        for (int l = 0; l < 4; ++l)
          acc[j][l] += av[j] * bv[l];
    }
    __syncthreads();
  }

  float* __restrict__ out = phi + (size_t)c * M_DIM * M_DIM;
#pragma unroll
  for (int j = 0; j < 4; ++j) {
    float4 o = make_float4(acc[j][0], acc[j][1], acc[j][2], acc[j][3]);
    *(float4*)&out[(size_t)(tm + ty * 4 + j) * M_DIM + tn + tx * 4] = o;
  }
}

// ---------------------------------------------------------------------------
// Kernel 3: mu[c] = sum feat_i ; count[c] = n_c
// ---------------------------------------------------------------------------
__global__ __launch_bounds__(128) void mu_count_kernel(
    const float* __restrict__ feat, const int* __restrict__ counts,
    const int* __restrict__ idx, float* __restrict__ mu,
    float* __restrict__ cnt_out) {
  const int c = blockIdx.x;
  const int t = threadIdx.x;            // 128 threads x float4 = 512 cols
  const int n = counts[c];
  const int* __restrict__ id = idx + c * B_N;
  float4 acc = make_float4(0.f, 0.f, 0.f, 0.f);
  for (int s = 0; s < n; ++s) {
    float4 v = *(const float4*)&feat[(size_t)id[s] * M_DIM + t * 4];
    acc.x += v.x; acc.y += v.y; acc.z += v.z; acc.w += v.w;
  }
  *(float4*)&mu[(size_t)c * M_DIM + t * 4] = acc;
  if (t == 0) cnt_out[c] = (float)n;
}

// ---------------------------------------------------------------------------
extern "C" void kernel_launch(void* const* d_in, const int* in_sizes, int n_in,
                              void* d_out, int out_size, void* d_ws,
                              size_t ws_size, hipStream_t stream) {
  const float* X      = (const float*)d_in[0];
  const float* W      = (const float*)d_in[1];
  const int*   labels = (const int*)d_in[2];

  float* out = (float*)d_out;
  float* phi = out;                                     // C*M*M
  float* mu  = out + (size_t)C_N * M_DIM * M_DIM;       // C*M
  float* cnt = mu + (size_t)C_N * M_DIM;                // C

  float* feat   = (float*)d_ws;                         // B*M fp32 = 2 MB
  int*   counts = (int*)((char*)d_ws + (size_t)B_N * M_DIM * sizeof(float));
  int*   idx    = counts + 128;                         // C*B ints = 400 KB

  hipLaunchKernelGGL(build_index_kernel, dim3(1), dim3(128), 0, stream,
                     labels, counts, idx);
  hipLaunchKernelGGL(feat_gemm_kernel, dim3(512), dim3(128), 0, stream,
                     X, W, feat);
  hipLaunchKernelGGL(phi_kernel, dim3(64, C_N), dim3(256), 0, stream,
                     feat, counts, idx, phi);
  hipLaunchKernelGGL(mu_count_kernel, dim3(C_N), dim3(128), 0, stream,
                     feat, counts, idx, mu, cnt);
}

// Round 2
// 84.545 us; speedup vs baseline: 1.5980x; 1.5980x over previous
//
#include <hip/hip_runtime.h>

#define B_N   1024
#define F_DIMC 768
#define M_DIM  512
#define C_N    100

// ---------------------------------------------------------------------------
// Kernel 0: per-class index lists (deterministic: ascending sample order)
// Rank-based scatter, labels staged in LDS. 1 block, 1024 threads.
// ---------------------------------------------------------------------------
__global__ __launch_bounds__(1024) void build_index_kernel(
    const int* __restrict__ labels, int* __restrict__ counts,
    int* __restrict__ idx) {
  __shared__ int lab[B_N];
  const int t = threadIdx.x;
  lab[t] = labels[t];
  __syncthreads();
  const int mylab = lab[t];
  int rank = 0;
  for (int j = 0; j < t; ++j) rank += (lab[j] == mylab) ? 1 : 0;
  idx[mylab * B_N + rank] = t;
  if (t < C_N) {
    int cnt = 0;
#pragma unroll 8
    for (int j = 0; j < B_N; ++j) cnt += (lab[j] == t) ? 1 : 0;
    counts[t] = cnt;
  }
}

// ---------------------------------------------------------------------------
// Kernel 1: feat = relu(X @ W)   [1024,768] x [768,512] -> [1024,512] fp32
// 32x32 tile, BK=16, 128 threads, 2x4 acc per thread, grid 512 blocks.
// ---------------------------------------------------------------------------
__global__ __launch_bounds__(128) void feat_gemm_kernel(
    const float* __restrict__ X, const float* __restrict__ W,
    float* __restrict__ feat) {
  __shared__ float As[16][36];  // A^T tile (k-major), padded
  __shared__ float Bs[16][32];

  const int bm = (int)(blockIdx.x >> 4) * 32;  // 32 row blocks
  const int bn = (int)(blockIdx.x & 15) * 32;  // 16 col blocks
  const int t  = threadIdx.x;
  const int tx = t & 7;    // col group (x4)
  const int ty = t >> 3;   // row group (x2)

  const int arow = t >> 2, akq = (t & 3) * 4;   // A tile load map
  const int bkr  = t >> 3, bnq = (t & 7) * 4;   // B tile load map

  float acc[2][4] = {};

  for (int k0 = 0; k0 < F_DIMC; k0 += 16) {
    float4 a = *(const float4*)&X[(size_t)(bm + arow) * F_DIMC + k0 + akq];
    As[akq + 0][arow] = a.x;
    As[akq + 1][arow] = a.y;
    As[akq + 2][arow] = a.z;
    As[akq + 3][arow] = a.w;
    *(float4*)&Bs[bkr][bnq] =
        *(const float4*)&W[(size_t)(k0 + bkr) * M_DIM + bn + bnq];
    __syncthreads();
#pragma unroll
    for (int kk = 0; kk < 16; ++kk) {
      float2 av = *(const float2*)&As[kk][ty * 2];
      float4 bv = *(const float4*)&Bs[kk][tx * 4];
      acc[0][0] += av.x * bv.x;
      acc[0][1] += av.x * bv.y;
      acc[0][2] += av.x * bv.z;
      acc[0][3] += av.x * bv.w;
      acc[1][0] += av.y * bv.x;
      acc[1][1] += av.y * bv.y;
      acc[1][2] += av.y * bv.z;
      acc[1][3] += av.y * bv.w;
    }
    __syncthreads();
  }

#pragma unroll
  for (int j = 0; j < 2; ++j) {
    float4 o;
    o.x = fmaxf(acc[j][0], 0.0f);
    o.y = fmaxf(acc[j][1], 0.0f);
    o.z = fmaxf(acc[j][2], 0.0f);
    o.w = fmaxf(acc[j][3], 0.0f);
    *(float4*)&feat[(size_t)(bm + ty * 2 + j) * M_DIM + bn + tx * 4] = o;
  }
}

// ---------------------------------------------------------------------------
// Kernel 2: phi[c] = sum_{i in class c} feat_i^T feat_i
// grid = (64 tiles of 64x64, C classes); 256 threads; 4x4 acc per thread.
// ---------------------------------------------------------------------------
__global__ __launch_bounds__(256) void phi_kernel(
    const float* __restrict__ feat, const int* __restrict__ counts,
    const int* __restrict__ idx, float* __restrict__ phi) {
  const int c    = blockIdx.y;
  const int tile = blockIdx.x;          // 0..63
  const int tm   = (tile >> 3) * 64;
  const int tn   = (tile & 7) * 64;
  const int n    = counts[c];
  const int* __restrict__ id = idx + c * B_N;

  __shared__ float As[16][64];
  __shared__ float Bs[16][64];

  const int t  = threadIdx.x;
  const int tx = t & 15;   // col group (x4)
  const int ty = t >> 4;   // row group (x4)

  float acc[4][4] = {};

  for (int s0 = 0; s0 < n; s0 += 16) {
    const int chunk  = min(16, n - s0);
    const int nslots = chunk * 32;      // float4 slots this chunk
    for (int v = t; v < nslots; v += 256) {
      const int sl   = v >> 5;
      const int part = v & 31;
      const int i    = id[s0 + sl];
      if (part < 16)
        *(float4*)&As[sl][part * 4] =
            *(const float4*)&feat[(size_t)i * M_DIM + tm + part * 4];
      else
        *(float4*)&Bs[sl][(part - 16) * 4] =
            *(const float4*)&feat[(size_t)i * M_DIM + tn + (part - 16) * 4];
    }
    __syncthreads();
    for (int sl = 0; sl < chunk; ++sl) {
      float4 a  = *(const float4*)&As[sl][ty * 4];
      float4 b4 = *(const float4*)&Bs[sl][tx * 4];
      float av[4] = {a.x, a.y, a.z, a.w};
      float bv[4] = {b4.x, b4.y, b4.z, b4.w};
#pragma unroll
      for (int j = 0; j < 4; ++j)
#pragma unroll
        for (int l = 0; l < 4; ++l)
          acc[j][l] += av[j] * bv[l];
    }
    __syncthreads();
  }

  float* __restrict__ out = phi + (size_t)c * M_DIM * M_DIM;
#pragma unroll
  for (int j = 0; j < 4; ++j) {
    float4 o = make_float4(acc[j][0], acc[j][1], acc[j][2], acc[j][3]);
    *(float4*)&out[(size_t)(tm + ty * 4 + j) * M_DIM + tn + tx * 4] = o;
  }
}

// ---------------------------------------------------------------------------
// Kernel 3: mu[c] = sum feat_i ; count[c] = n_c
// ---------------------------------------------------------------------------
__global__ __launch_bounds__(128) void mu_count_kernel(
    const float* __restrict__ feat, const int* __restrict__ counts,
    const int* __restrict__ idx, float* __restrict__ mu,
    float* __restrict__ cnt_out) {
  const int c = blockIdx.x;
  const int t = threadIdx.x;            // 128 threads x float4 = 512 cols
  const int n = counts[c];
  const int* __restrict__ id = idx + c * B_N;
  float4 acc = make_float4(0.f, 0.f, 0.f, 0.f);
  for (int s = 0; s < n; ++s) {
    float4 v = *(const float4*)&feat[(size_t)id[s] * M_DIM + t * 4];
    acc.x += v.x; acc.y += v.y; acc.z += v.z; acc.w += v.w;
  }
  *(float4*)&mu[(size_t)c * M_DIM + t * 4] = acc;
  if (t == 0) cnt_out[c] = (float)n;
}

// ---------------------------------------------------------------------------
extern "C" void kernel_launch(void* const* d_in, const int* in_sizes, int n_in,
                              void* d_out, int out_size, void* d_ws,
                              size_t ws_size, hipStream_t stream) {
  const float* X      = (const float*)d_in[0];
  const float* W      = (const float*)d_in[1];
  const int*   labels = (const int*)d_in[2];

  float* out = (float*)d_out;
  float* phi = out;                                     // C*M*M
  float* mu  = out + (size_t)C_N * M_DIM * M_DIM;       // C*M
  float* cnt = mu + (size_t)C_N * M_DIM;                // C

  float* feat   = (float*)d_ws;                         // B*M fp32 = 2 MB
  int*   counts = (int*)((char*)d_ws + (size_t)B_N * M_DIM * sizeof(float));
  int*   idx    = counts + 128;                         // C*B ints = 400 KB

  hipLaunchKernelGGL(build_index_kernel, dim3(1), dim3(1024), 0, stream,
                     labels, counts, idx);
  hipLaunchKernelGGL(feat_gemm_kernel, dim3(512), dim3(128), 0, stream,
                     X, W, feat);
  hipLaunchKernelGGL(phi_kernel, dim3(64, C_N), dim3(256), 0, stream,
                     feat, counts, idx, phi);
  hipLaunchKernelGGL(mu_count_kernel, dim3(C_N), dim3(128), 0, stream,
                     feat, counts, idx, mu, cnt);
}

// Round 3
// 62.240 us; speedup vs baseline: 2.1707x; 1.3584x over previous
//
#include <hip/hip_runtime.h>

#define B_N    1024
#define F_DIMC 768
#define M_DIM  512
#define C_N    100
#define NT     (F_DIMC / 32)   // 24 k-steps of BK=32

// ---------------------------------------------------------------------------
// Kernel 1: fused  feat = relu(X @ W)  +  per-class index build.
// GEMM: blocks 0..255, 32x64 tile, 256 thr, BK=32, double-buffered LDS.
// Index: block 256 (rank-based stable scatter, labels in LDS).
// ---------------------------------------------------------------------------
__global__ __launch_bounds__(256) void gemm_index_kernel(
    const float* __restrict__ X, const float* __restrict__ W,
    const int* __restrict__ labels, float* __restrict__ feat,
    int* __restrict__ counts, int* __restrict__ idx) {
  __shared__ float As[2][32][36];  // k-major A tile
  __shared__ float Bs[2][32][64];
  __shared__ int   lab[B_N];

  const int t = threadIdx.x;

  if (blockIdx.x == 256) {  // ---- index path ----
    for (int i = t; i < B_N; i += 256) lab[i] = labels[i];
    __syncthreads();
#pragma unroll
    for (int r = 0; r < 4; ++r) {
      const int i  = t + r * 256;
      const int li = lab[i];
      int rank = 0;
      for (int j = 0; j < i; ++j) rank += (lab[j] == li) ? 1 : 0;
      idx[li * B_N + rank] = i;
    }
    if (t < C_N) {
      int cnt = 0;
#pragma unroll 8
      for (int j = 0; j < B_N; ++j) cnt += (lab[j] == t) ? 1 : 0;
      counts[t] = cnt;
    }
    return;
  }

  // ---- GEMM path ----
  const int bm = (int)(blockIdx.x >> 3) * 32;  // 32 row tiles
  const int bn = (int)(blockIdx.x & 7) * 64;   // 8 col tiles
  const int tx = t & 15;   // col group (x4) -> 64 cols
  const int ty = t >> 4;   // row group (x2) -> 32 rows

  // staging maps
  const int ar  = t >> 3;        // A row 0..31
  const int akq = (t & 7) * 4;   // A k-quad
  const int bk0 = t >> 4;        // B k-row (slot t)
  const int bk1 = (t + 256) >> 4;
  const int bnq = (t & 15) * 4;  // B col-quad

  const float* __restrict__ Arow = X + (size_t)(bm + ar) * F_DIMC + akq;
  const float* __restrict__ Bcol = W + bn + bnq;

  float4 pa  = *(const float4*)(Arow);
  float4 pb0 = *(const float4*)(Bcol + (size_t)bk0 * M_DIM);
  float4 pb1 = *(const float4*)(Bcol + (size_t)bk1 * M_DIM);

  float acc[2][4] = {};

  {  // stage tile 0 into buf 0
    As[0][akq + 0][ar] = pa.x;
    As[0][akq + 1][ar] = pa.y;
    As[0][akq + 2][ar] = pa.z;
    As[0][akq + 3][ar] = pa.w;
    *(float4*)&Bs[0][bk0][bnq] = pb0;
    *(float4*)&Bs[0][bk1][bnq] = pb1;
  }
  __syncthreads();

  for (int it = 0; it < NT; ++it) {
    const int cur = it & 1;
    if (it + 1 < NT) {  // prefetch next tile into registers
      const int k0 = (it + 1) * 32;
      pa  = *(const float4*)(Arow + k0);
      pb0 = *(const float4*)(Bcol + (size_t)(k0 + bk0) * M_DIM);
      pb1 = *(const float4*)(Bcol + (size_t)(k0 + bk1) * M_DIM);
    }
#pragma unroll
    for (int kk = 0; kk < 32; ++kk) {
      float2 av = *(const float2*)&As[cur][kk][ty * 2];
      float4 bv = *(const float4*)&Bs[cur][kk][tx * 4];
      acc[0][0] += av.x * bv.x;
      acc[0][1] += av.x * bv.y;
      acc[0][2] += av.x * bv.z;
      acc[0][3] += av.x * bv.w;
      acc[1][0] += av.y * bv.x;
      acc[1][1] += av.y * bv.y;
      acc[1][2] += av.y * bv.z;
      acc[1][3] += av.y * bv.w;
    }
    if (it + 1 < NT) {
      const int nxt = cur ^ 1;
      As[nxt][akq + 0][ar] = pa.x;
      As[nxt][akq + 1][ar] = pa.y;
      As[nxt][akq + 2][ar] = pa.z;
      As[nxt][akq + 3][ar] = pa.w;
      *(float4*)&Bs[nxt][bk0][bnq] = pb0;
      *(float4*)&Bs[nxt][bk1][bnq] = pb1;
    }
    __syncthreads();
  }

#pragma unroll
  for (int j = 0; j < 2; ++j) {
    float4 o;
    o.x = fmaxf(acc[j][0], 0.0f);
    o.y = fmaxf(acc[j][1], 0.0f);
    o.z = fmaxf(acc[j][2], 0.0f);
    o.w = fmaxf(acc[j][3], 0.0f);
    *(float4*)&feat[(size_t)(bm + ty * 2 + j) * M_DIM + bn + tx * 4] = o;
  }
}

// ---------------------------------------------------------------------------
// Kernel 2: fused phi + mu + count.
// grid = (65, C): tiles 0..63 -> 64x64 phi tile; tile 64 -> mu/count row.
// ---------------------------------------------------------------------------
__global__ __launch_bounds__(256) void phi_mu_kernel(
    const float* __restrict__ feat, const int* __restrict__ counts,
    const int* __restrict__ idx, float* __restrict__ phi,
    float* __restrict__ mu, float* __restrict__ cnt_out) {
  const int c = blockIdx.y;
  const int tile = blockIdx.x;  // 0..64
  const int n = counts[c];
  const int* __restrict__ id = idx + c * B_N;
  const int t = threadIdx.x;

  if (tile == 64) {  // ---- mu / count path ----
    float2 acc = make_float2(0.f, 0.f);
    for (int s = 0; s < n; ++s) {
      float2 v = *(const float2*)&feat[(size_t)id[s] * M_DIM + t * 2];
      acc.x += v.x;
      acc.y += v.y;
    }
    *(float2*)&mu[(size_t)c * M_DIM + t * 2] = acc;
    if (t == 0) cnt_out[c] = (float)n;
    return;
  }

  // ---- phi tile path ----
  const int tm = (tile >> 3) * 64;
  const int tn = (tile & 7) * 64;

  __shared__ float As[16][64];
  __shared__ float Bs[16][64];

  const int tx = t & 15;   // col group (x4)
  const int ty = t >> 4;   // row group (x4)

  float acc[4][4] = {};

  for (int s0 = 0; s0 < n; s0 += 16) {
    const int chunk  = min(16, n - s0);
    const int nslots = chunk * 32;  // float4 slots
    for (int v = t; v < nslots; v += 256) {
      const int sl   = v >> 5;
      const int part = v & 31;
      const int i    = id[s0 + sl];
      if (part < 16)
        *(float4*)&As[sl][part * 4] =
            *(const float4*)&feat[(size_t)i * M_DIM + tm + part * 4];
      else
        *(float4*)&Bs[sl][(part - 16) * 4] =
            *(const float4*)&feat[(size_t)i * M_DIM + tn + (part - 16) * 4];
    }
    __syncthreads();
    for (int sl = 0; sl < chunk; ++sl) {
      float4 a  = *(const float4*)&As[sl][ty * 4];
      float4 b4 = *(const float4*)&Bs[sl][tx * 4];
      float av[4] = {a.x, a.y, a.z, a.w};
      float bv[4] = {b4.x, b4.y, b4.z, b4.w};
#pragma unroll
      for (int j = 0; j < 4; ++j)
#pragma unroll
        for (int l = 0; l < 4; ++l)
          acc[j][l] += av[j] * bv[l];
    }
    __syncthreads();
  }

  float* __restrict__ out = phi + (size_t)c * M_DIM * M_DIM;
#pragma unroll
  for (int j = 0; j < 4; ++j) {
    float4 o = make_float4(acc[j][0], acc[j][1], acc[j][2], acc[j][3]);
    *(float4*)&out[(size_t)(tm + ty * 4 + j) * M_DIM + tn + tx * 4] = o;
  }
}

// ---------------------------------------------------------------------------
extern "C" void kernel_launch(void* const* d_in, const int* in_sizes, int n_in,
                              void* d_out, int out_size, void* d_ws,
                              size_t ws_size, hipStream_t stream) {
  const float* X      = (const float*)d_in[0];
  const float* W      = (const float*)d_in[1];
  const int*   labels = (const int*)d_in[2];

  float* out = (float*)d_out;
  float* phi = out;                                // C*M*M
  float* mu  = out + (size_t)C_N * M_DIM * M_DIM;  // C*M
  float* cnt = mu + (size_t)C_N * M_DIM;           // C

  float* feat   = (float*)d_ws;                    // B*M fp32 = 2 MB
  int*   counts = (int*)((char*)d_ws + (size_t)B_N * M_DIM * sizeof(float));
  int*   idx    = counts + 128;                    // C*B ints = 400 KB

  hipLaunchKernelGGL(gemm_index_kernel, dim3(257), dim3(256), 0, stream,
                     X, W, labels, feat, counts, idx);
  hipLaunchKernelGGL(phi_mu_kernel, dim3(65, C_N), dim3(256), 0, stream,
                     feat, counts, idx, phi, mu, cnt);
}

// Round 4
// 53.923 us; speedup vs baseline: 2.5055x; 1.1542x over previous
//
#include <hip/hip_runtime.h>

#define B_N    1024
#define F_DIMC 768
#define M_DIM  512
#define C_N    100
#define NT     (F_DIMC / 32)   // 24 k-steps of BK=32
#define NGEMM  256             // GEMM blocks; index blocks follow
#define NIDX   25              // 25 blocks x 4 waves = 100 classes

// ---------------------------------------------------------------------------
// Kernel 1: fused  feat = relu(X @ W)  +  per-class index build.
// GEMM: blocks 0..255, 32x64 tile, 256 thr, BK=32, double-buffered LDS.
// Index: blocks 256..280, one wave per class, ballot-based stable rank.
// ---------------------------------------------------------------------------
__global__ __launch_bounds__(256) void gemm_index_kernel(
    const float* __restrict__ X, const float* __restrict__ W,
    const int* __restrict__ labels, float* __restrict__ feat,
    int* __restrict__ counts, int* __restrict__ idx) {
  __shared__ float As[2][32][36];  // k-major A tile
  __shared__ float Bs[2][32][64];
  __shared__ int   lab[B_N];

  const int t = threadIdx.x;

  if (blockIdx.x >= NGEMM) {  // ---- index path: wave-parallel ballot rank ----
    for (int i = t; i < B_N; i += 256) lab[i] = labels[i];
    __syncthreads();
    const int w    = t >> 6;
    const int lane = t & 63;
    const int c    = ((int)blockIdx.x - NGEMM) * 4 + w;
    if (c < C_N) {
      int base = 0;
      for (int ch = 0; ch < 16; ++ch) {
        const int j = ch * 64 + lane;
        const bool hit = (lab[j] == c);
        const unsigned long long mask = __ballot(hit);
        if (hit) {
          const int r = __popcll(mask & ((1ull << lane) - 1ull));
          idx[c * B_N + base + r] = j;
        }
        base += __popcll(mask);
      }
      if (lane == 0) counts[c] = base;
    }
    return;
  }

  // ---- GEMM path ----
  const int bm = (int)(blockIdx.x >> 3) * 32;  // 32 row tiles
  const int bn = (int)(blockIdx.x & 7) * 64;   // 8 col tiles
  const int tx = t & 15;   // col group (x4) -> 64 cols
  const int ty = t >> 4;   // row group (x2) -> 32 rows

  // staging maps
  const int ar  = t >> 3;        // A row 0..31
  const int akq = (t & 7) * 4;   // A k-quad
  const int bk0 = t >> 4;        // B k-row (slot t)
  const int bk1 = (t + 256) >> 4;
  const int bnq = (t & 15) * 4;  // B col-quad

  const float* __restrict__ Arow = X + (size_t)(bm + ar) * F_DIMC + akq;
  const float* __restrict__ Bcol = W + bn + bnq;

  float4 pa  = *(const float4*)(Arow);
  float4 pb0 = *(const float4*)(Bcol + (size_t)bk0 * M_DIM);
  float4 pb1 = *(const float4*)(Bcol + (size_t)bk1 * M_DIM);

  float acc[2][4] = {};

  {  // stage tile 0 into buf 0
    As[0][akq + 0][ar] = pa.x;
    As[0][akq + 1][ar] = pa.y;
    As[0][akq + 2][ar] = pa.z;
    As[0][akq + 3][ar] = pa.w;
    *(float4*)&Bs[0][bk0][bnq] = pb0;
    *(float4*)&Bs[0][bk1][bnq] = pb1;
  }
  __syncthreads();

  for (int it = 0; it < NT; ++it) {
    const int cur = it & 1;
    if (it + 1 < NT) {  // prefetch next tile into registers
      const int k0 = (it + 1) * 32;
      pa  = *(const float4*)(Arow + k0);
      pb0 = *(const float4*)(Bcol + (size_t)(k0 + bk0) * M_DIM);
      pb1 = *(const float4*)(Bcol + (size_t)(k0 + bk1) * M_DIM);
    }
#pragma unroll
    for (int kk = 0; kk < 32; ++kk) {
      float2 av = *(const float2*)&As[cur][kk][ty * 2];
      float4 bv = *(const float4*)&Bs[cur][kk][tx * 4];
      acc[0][0] += av.x * bv.x;
      acc[0][1] += av.x * bv.y;
      acc[0][2] += av.x * bv.z;
      acc[0][3] += av.x * bv.w;
      acc[1][0] += av.y * bv.x;
      acc[1][1] += av.y * bv.y;
      acc[1][2] += av.y * bv.z;
      acc[1][3] += av.y * bv.w;
    }
    if (it + 1 < NT) {
      const int nxt = cur ^ 1;
      As[nxt][akq + 0][ar] = pa.x;
      As[nxt][akq + 1][ar] = pa.y;
      As[nxt][akq + 2][ar] = pa.z;
      As[nxt][akq + 3][ar] = pa.w;
      *(float4*)&Bs[nxt][bk0][bnq] = pb0;
      *(float4*)&Bs[nxt][bk1][bnq] = pb1;
    }
    __syncthreads();
  }

#pragma unroll
  for (int j = 0; j < 2; ++j) {
    float4 o;
    o.x = fmaxf(acc[j][0], 0.0f);
    o.y = fmaxf(acc[j][1], 0.0f);
    o.z = fmaxf(acc[j][2], 0.0f);
    o.w = fmaxf(acc[j][3], 0.0f);
    *(float4*)&feat[(size_t)(bm + ty * 2 + j) * M_DIM + bn + tx * 4] = o;
  }
}

// ---------------------------------------------------------------------------
// Kernel 2: fused phi + mu + count.
// grid = (65, C): tiles 0..63 -> 64x64 phi tile; tile 64 -> mu/count row.
// ---------------------------------------------------------------------------
__global__ __launch_bounds__(256) void phi_mu_kernel(
    const float* __restrict__ feat, const int* __restrict__ counts,
    const int* __restrict__ idx, float* __restrict__ phi,
    float* __restrict__ mu, float* __restrict__ cnt_out) {
  const int c = blockIdx.y;
  const int tile = blockIdx.x;  // 0..64
  const int n = counts[c];
  const int* __restrict__ id = idx + c * B_N;
  const int t = threadIdx.x;

  if (tile == 64) {  // ---- mu / count path ----
    float2 acc = make_float2(0.f, 0.f);
    for (int s = 0; s < n; ++s) {
      float2 v = *(const float2*)&feat[(size_t)id[s] * M_DIM + t * 2];
      acc.x += v.x;
      acc.y += v.y;
    }
    *(float2*)&mu[(size_t)c * M_DIM + t * 2] = acc;
    if (t == 0) cnt_out[c] = (float)n;
    return;
  }

  // ---- phi tile path ----
  const int tm = (tile >> 3) * 64;
  const int tn = (tile & 7) * 64;

  __shared__ float As[16][64];
  __shared__ float Bs[16][64];

  const int tx = t & 15;   // col group (x4)
  const int ty = t >> 4;   // row group (x4)

  float acc[4][4] = {};

  for (int s0 = 0; s0 < n; s0 += 16) {
    const int chunk  = min(16, n - s0);
    const int nslots = chunk * 32;  // float4 slots
    for (int v = t; v < nslots; v += 256) {
      const int sl   = v >> 5;
      const int part = v & 31;
      const int i    = id[s0 + sl];
      if (part < 16)
        *(float4*)&As[sl][part * 4] =
            *(const float4*)&feat[(size_t)i * M_DIM + tm + part * 4];
      else
        *(float4*)&Bs[sl][(part - 16) * 4] =
            *(const float4*)&feat[(size_t)i * M_DIM + tn + (part - 16) * 4];
    }
    __syncthreads();
    for (int sl = 0; sl < chunk; ++sl) {
      float4 a  = *(const float4*)&As[sl][ty * 4];
      float4 b4 = *(const float4*)&Bs[sl][tx * 4];
      float av[4] = {a.x, a.y, a.z, a.w};
      float bv[4] = {b4.x, b4.y, b4.z, b4.w};
#pragma unroll
      for (int j = 0; j < 4; ++j)
#pragma unroll
        for (int l = 0; l < 4; ++l)
          acc[j][l] += av[j] * bv[l];
    }
    __syncthreads();
  }

  float* __restrict__ out = phi + (size_t)c * M_DIM * M_DIM;
#pragma unroll
  for (int j = 0; j < 4; ++j) {
    float4 o = make_float4(acc[j][0], acc[j][1], acc[j][2], acc[j][3]);
    *(float4*)&out[(size_t)(tm + ty * 4 + j) * M_DIM + tn + tx * 4] = o;
  }
}

// ---------------------------------------------------------------------------
extern "C" void kernel_launch(void* const* d_in, const int* in_sizes, int n_in,
                              void* d_out, int out_size, void* d_ws,
                              size_t ws_size, hipStream_t stream) {
  const float* X      = (const float*)d_in[0];
  const float* W      = (const float*)d_in[1];
  const int*   labels = (const int*)d_in[2];

  float* out = (float*)d_out;
  float* phi = out;                                // C*M*M
  float* mu  = out + (size_t)C_N * M_DIM * M_DIM;  // C*M
  float* cnt = mu + (size_t)C_N * M_DIM;           // C

  float* feat   = (float*)d_ws;                    // B*M fp32 = 2 MB
  int*   counts = (int*)((char*)d_ws + (size_t)B_N * M_DIM * sizeof(float));
  int*   idx    = counts + 128;                    // C*B ints = 400 KB

  hipLaunchKernelGGL(gemm_index_kernel, dim3(NGEMM + NIDX), dim3(256), 0,
                     stream, X, W, labels, feat, counts, idx);
  hipLaunchKernelGGL(phi_mu_kernel, dim3(65, C_N), dim3(256), 0, stream,
                     feat, counts, idx, phi, mu, cnt);
}

// Round 5
// 51.032 us; speedup vs baseline: 2.6474x; 1.0567x over previous
//
#include <hip/hip_runtime.h>

#define B_N    1024
#define F_DIMC 768
#define M_DIM  512
#define C_N    100
#define KHALF  (F_DIMC / 2)     // 384 per K-split half
#define NT2    (KHALF / 32)     // 12 k-steps of BK=32
#define NGEMM  512              // 256 tiles x 2 K-halves
#define NIDX   25               // 25 blocks x 4 waves = 100 classes

// ---------------------------------------------------------------------------
// Kernel 1: partial GEMM (K-split x2, no relu) + per-class index build.
// blocks 0..511: 32x64 tile, half-K each, 256 thr, double-buffered LDS.
// blocks 512..536: one wave per class, ballot-based stable rank.
// ---------------------------------------------------------------------------
__global__ __launch_bounds__(256) void gemm_index_kernel(
    const float* __restrict__ X, const float* __restrict__ W,
    const int* __restrict__ labels, float* __restrict__ part,
    int* __restrict__ counts, int* __restrict__ idx) {
  __shared__ float As[2][32][36];  // k-major A tile
  __shared__ float Bs[2][32][64];
  __shared__ int   lab[B_N];

  const int t = threadIdx.x;

  if (blockIdx.x >= NGEMM) {  // ---- index path ----
    for (int i = t; i < B_N; i += 256) lab[i] = labels[i];
    __syncthreads();
    const int w    = t >> 6;
    const int lane = t & 63;
    const int c    = ((int)blockIdx.x - NGEMM) * 4 + w;
    if (c < C_N) {
      int base = 0;
      for (int ch = 0; ch < 16; ++ch) {
        const int j = ch * 64 + lane;
        const bool hit = (lab[j] == c);
        const unsigned long long mask = __ballot(hit);
        if (hit) {
          const int r = __popcll(mask & ((1ull << lane) - 1ull));
          idx[c * B_N + base + r] = j;
        }
        base += __popcll(mask);
      }
      if (lane == 0) counts[c] = base;
    }
    return;
  }

  // ---- GEMM path ----
  const int kb   = (int)blockIdx.x >> 8;        // K-half 0/1
  const int tile = (int)blockIdx.x & 255;
  const int bm = (tile >> 3) * 32;
  const int bn = (tile & 7) * 64;
  const int tx = t & 15;   // col group (x4) -> 64 cols
  const int ty = t >> 4;   // row group (x2) -> 32 rows

  const int ar  = t >> 3;        // A row 0..31
  const int akq = (t & 7) * 4;   // A k-quad
  const int bk0 = t >> 4;        // B k-rows
  const int bk1 = bk0 + 16;
  const int bnq = (t & 15) * 4;  // B col-quad

  const float* __restrict__ Arow =
      X + (size_t)(bm + ar) * F_DIMC + kb * KHALF + akq;
  const float* __restrict__ Bcol =
      W + (size_t)kb * KHALF * M_DIM + bn + bnq;

  float4 pa  = *(const float4*)(Arow);
  float4 pb0 = *(const float4*)(Bcol + (size_t)bk0 * M_DIM);
  float4 pb1 = *(const float4*)(Bcol + (size_t)bk1 * M_DIM);

  float acc[2][4] = {};

  As[0][akq + 0][ar] = pa.x;
  As[0][akq + 1][ar] = pa.y;
  As[0][akq + 2][ar] = pa.z;
  As[0][akq + 3][ar] = pa.w;
  *(float4*)&Bs[0][bk0][bnq] = pb0;
  *(float4*)&Bs[0][bk1][bnq] = pb1;
  __syncthreads();

  for (int it = 0; it < NT2; ++it) {
    const int cur = it & 1;
    if (it + 1 < NT2) {
      const int k0 = (it + 1) * 32;
      pa  = *(const float4*)(Arow + k0);
      pb0 = *(const float4*)(Bcol + (size_t)(k0 + bk0) * M_DIM);
      pb1 = *(const float4*)(Bcol + (size_t)(k0 + bk1) * M_DIM);
    }
#pragma unroll
    for (int kk = 0; kk < 32; ++kk) {
      float2 av = *(const float2*)&As[cur][kk][ty * 2];
      float4 bv = *(const float4*)&Bs[cur][kk][tx * 4];
      acc[0][0] += av.x * bv.x;
      acc[0][1] += av.x * bv.y;
      acc[0][2] += av.x * bv.z;
      acc[0][3] += av.x * bv.w;
      acc[1][0] += av.y * bv.x;
      acc[1][1] += av.y * bv.y;
      acc[1][2] += av.y * bv.z;
      acc[1][3] += av.y * bv.w;
    }
    if (it + 1 < NT2) {
      const int nxt = cur ^ 1;
      As[nxt][akq + 0][ar] = pa.x;
      As[nxt][akq + 1][ar] = pa.y;
      As[nxt][akq + 2][ar] = pa.z;
      As[nxt][akq + 3][ar] = pa.w;
      *(float4*)&Bs[nxt][bk0][bnq] = pb0;
      *(float4*)&Bs[nxt][bk1][bnq] = pb1;
    }
    __syncthreads();
  }

  float* __restrict__ dst = part + (size_t)kb * B_N * M_DIM;
#pragma unroll
  for (int j = 0; j < 2; ++j) {
    float4 o = make_float4(acc[j][0], acc[j][1], acc[j][2], acc[j][3]);
    *(float4*)&dst[(size_t)(bm + ty * 2 + j) * M_DIM + bn + tx * 4] = o;
  }
}

// ---------------------------------------------------------------------------
// Kernel 2: phi strips + mu/count. feat = relu(p0 + p1) built in staging.
// grid = (9, C): strips 0..7 -> 512x64 phi strip; strip 8 -> mu/count.
// 512 threads; strip path: 8x8 acc/thread, 16x512 LDS row stage.
// ---------------------------------------------------------------------------
__global__ __launch_bounds__(512, 4) void phi_mu_kernel(
    const float* __restrict__ p0, const float* __restrict__ p1,
    const int* __restrict__ counts, const int* __restrict__ idx,
    float* __restrict__ phi, float* __restrict__ mu,
    float* __restrict__ cnt_out) {
  const int c = blockIdx.y;
  const int n = counts[c];
  const int* __restrict__ id = idx + c * B_N;
  const int t = threadIdx.x;

  if (blockIdx.x == 8) {  // ---- mu / count path ----
    float acc = 0.f;
    for (int s = 0; s < n; ++s) {
      const size_t o = (size_t)id[s] * M_DIM + t;
      acc += fmaxf(p0[o] + p1[o], 0.f);
    }
    mu[(size_t)c * M_DIM + t] = acc;
    if (t == 0) cnt_out[c] = (float)n;
    return;
  }

  // ---- phi strip path: rows 0..511, cols c0..c0+63 ----
  const int c0 = (int)blockIdx.x * 64;
  const int rg = t >> 3;  // row group 0..63 (x8 rows)
  const int cg = t & 7;   // col group 0..7  (x8 cols)

  __shared__ float F[16][M_DIM];

  float acc[8][8] = {};

  for (int s0 = 0; s0 < n; s0 += 16) {
    const int chunk  = min(16, n - s0);
    const int nslots = chunk << 7;  // chunk * 128 float4 per row
    for (int v = t; v < nslots; v += 512) {
      const int sl   = v >> 7;
      const int part = (v & 127) << 2;
      const size_t o = (size_t)id[s0 + sl] * M_DIM + part;
      const float4 q0 = *(const float4*)&p0[o];
      const float4 q1 = *(const float4*)&p1[o];
      float4 f;
      f.x = fmaxf(q0.x + q1.x, 0.f);
      f.y = fmaxf(q0.y + q1.y, 0.f);
      f.z = fmaxf(q0.z + q1.z, 0.f);
      f.w = fmaxf(q0.w + q1.w, 0.f);
      *(float4*)&F[sl][part] = f;
    }
    __syncthreads();
    for (int sl = 0; sl < chunk; ++sl) {
      const float4 a0 = *(const float4*)&F[sl][rg * 8];
      const float4 a1 = *(const float4*)&F[sl][rg * 8 + 4];
      const float4 b0 = *(const float4*)&F[sl][c0 + cg * 8];
      const float4 b1 = *(const float4*)&F[sl][c0 + cg * 8 + 4];
      const float av[8] = {a0.x, a0.y, a0.z, a0.w, a1.x, a1.y, a1.z, a1.w};
      const float bv[8] = {b0.x, b0.y, b0.z, b0.w, b1.x, b1.y, b1.z, b1.w};
#pragma unroll
      for (int r = 0; r < 8; ++r)
#pragma unroll
        for (int q = 0; q < 8; ++q)
          acc[r][q] += av[r] * bv[q];
    }
    __syncthreads();
  }

  float* __restrict__ out = phi + (size_t)c * M_DIM * M_DIM + c0;
#pragma unroll
  for (int r = 0; r < 8; ++r) {
    const size_t row = (size_t)(rg * 8 + r) * M_DIM;
    *(float4*)&out[row + cg * 8] =
        make_float4(acc[r][0], acc[r][1], acc[r][2], acc[r][3]);
    *(float4*)&out[row + cg * 8 + 4] =
        make_float4(acc[r][4], acc[r][5], acc[r][6], acc[r][7]);
  }
}

// ---------------------------------------------------------------------------
extern "C" void kernel_launch(void* const* d_in, const int* in_sizes, int n_in,
                              void* d_out, int out_size, void* d_ws,
                              size_t ws_size, hipStream_t stream) {
  const float* X      = (const float*)d_in[0];
  const float* W      = (const float*)d_in[1];
  const int*   labels = (const int*)d_in[2];

  float* out = (float*)d_out;
  float* phi = out;                                // C*M*M
  float* mu  = out + (size_t)C_N * M_DIM * M_DIM;  // C*M
  float* cnt = mu + (size_t)C_N * M_DIM;           // C

  float* part   = (float*)d_ws;                    // 2 x B*M fp32 = 4 MB
  int*   counts = (int*)((char*)d_ws + (size_t)2 * B_N * M_DIM * sizeof(float));
  int*   idx    = counts + 128;                    // C*B ints

  hipLaunchKernelGGL(gemm_index_kernel, dim3(NGEMM + NIDX), dim3(256), 0,
                     stream, X, W, labels, part, counts, idx);
  hipLaunchKernelGGL(phi_mu_kernel, dim3(9, C_N), dim3(512), 0, stream,
                     part, part + (size_t)B_N * M_DIM, counts, idx,
                     phi, mu, cnt);
}

// Round 6
// 48.597 us; speedup vs baseline: 2.7801x; 1.0501x over previous
//
#include <hip/hip_runtime.h>

#define B_N    1024
#define F_DIMC 768
#define M_DIM  512
#define C_N    100
#define KHALF  (F_DIMC / 2)     // 384 per K-split half
#define NT2    (KHALF / 32)     // 12 k-steps of BK=32
#define NGEMM  512              // 256 tiles x 2 K-halves
#define NIDX   25               // 25 blocks x 4 waves = 100 classes

// ---------------------------------------------------------------------------
// Kernel 1: partial GEMM (K-split x2, no relu) + per-class index build.
// blocks 0..511: 32x64 tile, half-K each, 256 thr, double-buffered LDS.
// blocks 512..536: one wave per class, ballot-based stable rank.
// ---------------------------------------------------------------------------
__global__ __launch_bounds__(256) void gemm_index_kernel(
    const float* __restrict__ X, const float* __restrict__ W,
    const int* __restrict__ labels, float* __restrict__ part,
    int* __restrict__ counts, int* __restrict__ idx) {
  __shared__ float As[2][32][36];  // k-major A tile
  __shared__ float Bs[2][32][64];
  __shared__ int   lab[B_N];

  const int t = threadIdx.x;

  if (blockIdx.x >= NGEMM) {  // ---- index path ----
    for (int i = t; i < B_N; i += 256) lab[i] = labels[i];
    __syncthreads();
    const int w    = t >> 6;
    const int lane = t & 63;
    const int c    = ((int)blockIdx.x - NGEMM) * 4 + w;
    if (c < C_N) {
      int base = 0;
      for (int ch = 0; ch < 16; ++ch) {
        const int j = ch * 64 + lane;
        const bool hit = (lab[j] == c);
        const unsigned long long mask = __ballot(hit);
        if (hit) {
          const int r = __popcll(mask & ((1ull << lane) - 1ull));
          idx[c * B_N + base + r] = j;
        }
        base += __popcll(mask);
      }
      if (lane == 0) counts[c] = base;
    }
    return;
  }

  // ---- GEMM path ----
  const int kb   = (int)blockIdx.x >> 8;        // K-half 0/1
  const int tile = (int)blockIdx.x & 255;
  const int bm = (tile >> 3) * 32;
  const int bn = (tile & 7) * 64;
  const int tx = t & 15;   // col group (x4) -> 64 cols
  const int ty = t >> 4;   // row group (x2) -> 32 rows

  const int ar  = t >> 3;        // A row 0..31
  const int akq = (t & 7) * 4;   // A k-quad
  const int bk0 = t >> 4;        // B k-rows
  const int bk1 = bk0 + 16;
  const int bnq = (t & 15) * 4;  // B col-quad

  const float* __restrict__ Arow =
      X + (size_t)(bm + ar) * F_DIMC + kb * KHALF + akq;
  const float* __restrict__ Bcol =
      W + (size_t)kb * KHALF * M_DIM + bn + bnq;

  float4 pa  = *(const float4*)(Arow);
  float4 pb0 = *(const float4*)(Bcol + (size_t)bk0 * M_DIM);
  float4 pb1 = *(const float4*)(Bcol + (size_t)bk1 * M_DIM);

  float acc[2][4] = {};

  As[0][akq + 0][ar] = pa.x;
  As[0][akq + 1][ar] = pa.y;
  As[0][akq + 2][ar] = pa.z;
  As[0][akq + 3][ar] = pa.w;
  *(float4*)&Bs[0][bk0][bnq] = pb0;
  *(float4*)&Bs[0][bk1][bnq] = pb1;
  __syncthreads();

  for (int it = 0; it < NT2; ++it) {
    const int cur = it & 1;
    if (it + 1 < NT2) {
      const int k0 = (it + 1) * 32;
      pa  = *(const float4*)(Arow + k0);
      pb0 = *(const float4*)(Bcol + (size_t)(k0 + bk0) * M_DIM);
      pb1 = *(const float4*)(Bcol + (size_t)(k0 + bk1) * M_DIM);
    }
#pragma unroll
    for (int kk = 0; kk < 32; ++kk) {
      float2 av = *(const float2*)&As[cur][kk][ty * 2];
      float4 bv = *(const float4*)&Bs[cur][kk][tx * 4];
      acc[0][0] += av.x * bv.x;
      acc[0][1] += av.x * bv.y;
      acc[0][2] += av.x * bv.z;
      acc[0][3] += av.x * bv.w;
      acc[1][0] += av.y * bv.x;
      acc[1][1] += av.y * bv.y;
      acc[1][2] += av.y * bv.z;
      acc[1][3] += av.y * bv.w;
    }
    if (it + 1 < NT2) {
      const int nxt = cur ^ 1;
      As[nxt][akq + 0][ar] = pa.x;
      As[nxt][akq + 1][ar] = pa.y;
      As[nxt][akq + 2][ar] = pa.z;
      As[nxt][akq + 3][ar] = pa.w;
      *(float4*)&Bs[nxt][bk0][bnq] = pb0;
      *(float4*)&Bs[nxt][bk1][bnq] = pb1;
    }
    __syncthreads();
  }

  float* __restrict__ dst = part + (size_t)kb * B_N * M_DIM;
#pragma unroll
  for (int j = 0; j < 2; ++j) {
    float4 o = make_float4(acc[j][0], acc[j][1], acc[j][2], acc[j][3]);
    *(float4*)&dst[(size_t)(bm + ty * 2 + j) * M_DIM + bn + tx * 4] = o;
  }
}

// ---------------------------------------------------------------------------
// Kernel 2: phi row-panels + mu/count. feat = relu(p0 + p1) built in staging.
// grid = (17, C): panels 0..15 -> 32 rows x 512 cols (contiguous 64 KB of
// phi, nontemporal streamed); panel 16 -> mu/count.
// 256 threads; A-reads broadcast, B-reads scalar lane-consecutive (no bank
// conflicts), stores scalar nt (256 B contiguous per wave-instr).
// ---------------------------------------------------------------------------
__global__ __launch_bounds__(256, 4) void phi_mu_kernel(
    const float* __restrict__ p0, const float* __restrict__ p1,
    const int* __restrict__ counts, const int* __restrict__ idx,
    float* __restrict__ phi, float* __restrict__ mu,
    float* __restrict__ cnt_out) {
  const int c = blockIdx.y;
  const int n = counts[c];
  const int* __restrict__ id = idx + c * B_N;
  const int t = threadIdx.x;

  if (blockIdx.x == 16) {  // ---- mu / count path ----
    float2 acc = make_float2(0.f, 0.f);
    for (int s = 0; s < n; ++s) {
      const size_t o = (size_t)id[s] * M_DIM + t * 2;
      const float2 q0 = *(const float2*)&p0[o];
      const float2 q1 = *(const float2*)&p1[o];
      acc.x += fmaxf(q0.x + q1.x, 0.f);
      acc.y += fmaxf(q0.y + q1.y, 0.f);
    }
    *(float2*)&mu[(size_t)c * M_DIM + t * 2] = acc;
    if (t == 0) cnt_out[c] = (float)n;
    return;
  }

  // ---- phi row-panel path: rows 32*px..+32, all 512 cols ----
  const int px = (int)blockIdx.x;      // 0..15
  const int tr = t >> 6;               // wave id 0..3 -> 8-row group
  const int tc = t & 63;               // lane -> base col

  __shared__ float F[16][M_DIM];

  float acc[8][8] = {};                // [row r][col q]: col = tc + 64q

  for (int s0 = 0; s0 < n; s0 += 16) {
    const int chunk  = min(16, n - s0);
    const int nslots = chunk << 7;     // chunk * 128 float4 per row
    for (int v = t; v < nslots; v += 256) {
      const int sl   = v >> 7;
      const int fp   = (v & 127) << 2;
      const size_t o = (size_t)id[s0 + sl] * M_DIM + fp;
      const float4 q0 = *(const float4*)&p0[o];
      const float4 q1 = *(const float4*)&p1[o];
      float4 f;
      f.x = fmaxf(q0.x + q1.x, 0.f);
      f.y = fmaxf(q0.y + q1.y, 0.f);
      f.z = fmaxf(q0.z + q1.z, 0.f);
      f.w = fmaxf(q0.w + q1.w, 0.f);
      *(float4*)&F[sl][fp] = f;
    }
    __syncthreads();
    for (int sl = 0; sl < chunk; ++sl) {
      float av[8], bv[8];
#pragma unroll
      for (int r = 0; r < 8; ++r)
        av[r] = F[sl][px * 32 + tr * 8 + r];   // wave-broadcast
#pragma unroll
      for (int q = 0; q < 8; ++q)
        bv[q] = F[sl][tc + 64 * q];            // lane-consecutive
#pragma unroll
      for (int r = 0; r < 8; ++r)
#pragma unroll
        for (int q = 0; q < 8; ++q)
          acc[r][q] += av[r] * bv[q];
    }
    __syncthreads();
  }

  float* __restrict__ out = phi + (size_t)c * M_DIM * M_DIM;
#pragma unroll
  for (int r = 0; r < 8; ++r) {
    const size_t row = (size_t)(px * 32 + tr * 8 + r) * M_DIM;
#pragma unroll
    for (int q = 0; q < 8; ++q)
      __builtin_nontemporal_store(acc[r][q], &out[row + tc + 64 * q]);
  }
}

// ---------------------------------------------------------------------------
extern "C" void kernel_launch(void* const* d_in, const int* in_sizes, int n_in,
                              void* d_out, int out_size, void* d_ws,
                              size_t ws_size, hipStream_t stream) {
  const float* X      = (const float*)d_in[0];
  const float* W      = (const float*)d_in[1];
  const int*   labels = (const int*)d_in[2];

  float* out = (float*)d_out;
  float* phi = out;                                // C*M*M
  float* mu  = out + (size_t)C_N * M_DIM * M_DIM;  // C*M
  float* cnt = mu + (size_t)C_N * M_DIM;           // C

  float* part   = (float*)d_ws;                    // 2 x B*M fp32 = 4 MB
  int*   counts = (int*)((char*)d_ws + (size_t)2 * B_N * M_DIM * sizeof(float));
  int*   idx    = counts + 128;                    // C*B ints

  hipLaunchKernelGGL(gemm_index_kernel, dim3(NGEMM + NIDX), dim3(256), 0,
                     stream, X, W, labels, part, counts, idx);
  hipLaunchKernelGGL(phi_mu_kernel, dim3(17, C_N), dim3(256), 0, stream,
                     part, part + (size_t)B_N * M_DIM, counts, idx,
                     phi, mu, cnt);
}

// Round 8
// 47.236 us; speedup vs baseline: 2.8602x; 1.0288x over previous
//
#include <hip/hip_runtime.h>

#define B_N    1024
#define F_DIMC 768
#define M_DIM  512
#define C_N    100
#define KHALF  (F_DIMC / 2)     // 384 per K-split half
#define NT2    (KHALF / 32)     // 12 k-steps of BK=32
#define NGEMM  512              // 256 tiles x 2 K-halves
#define NIDX   25               // 25 blocks x 4 waves = 100 classes

typedef float f32x4 __attribute__((ext_vector_type(4)));

// ---------------------------------------------------------------------------
// Kernel 1: partial GEMM (K-split x2, no relu) + per-class index build.
// blocks 0..511: 32x64 tile, half-K each, 256 thr, double-buffered LDS.
// blocks 512..536: one wave per class, ballot-based stable rank.
// ---------------------------------------------------------------------------
__global__ __launch_bounds__(256) void gemm_index_kernel(
    const float* __restrict__ X, const float* __restrict__ W,
    const int* __restrict__ labels, float* __restrict__ part,
    int* __restrict__ counts, int* __restrict__ idx) {
  __shared__ float As[2][32][36];  // k-major A tile
  __shared__ float Bs[2][32][64];
  __shared__ int   lab[B_N];

  const int t = threadIdx.x;

  if (blockIdx.x >= NGEMM) {  // ---- index path ----
    for (int i = t; i < B_N; i += 256) lab[i] = labels[i];
    __syncthreads();
    const int w    = t >> 6;
    const int lane = t & 63;
    const int c    = ((int)blockIdx.x - NGEMM) * 4 + w;
    if (c < C_N) {
      int base = 0;
      for (int ch = 0; ch < 16; ++ch) {
        const int j = ch * 64 + lane;
        const bool hit = (lab[j] == c);
        const unsigned long long mask = __ballot(hit);
        if (hit) {
          const int r = __popcll(mask & ((1ull << lane) - 1ull));
          idx[c * B_N + base + r] = j;
        }
        base += __popcll(mask);
      }
      if (lane == 0) counts[c] = base;
    }
    return;
  }

  // ---- GEMM path ----
  const int kb   = (int)blockIdx.x >> 8;        // K-half 0/1
  const int tile = (int)blockIdx.x & 255;
  const int bm = (tile >> 3) * 32;
  const int bn = (tile & 7) * 64;
  const int tx = t & 15;   // col group (x4) -> 64 cols
  const int ty = t >> 4;   // row group (x2) -> 32 rows

  const int ar  = t >> 3;        // A row 0..31
  const int akq = (t & 7) * 4;   // A k-quad
  const int bk0 = t >> 4;        // B k-rows
  const int bk1 = bk0 + 16;
  const int bnq = (t & 15) * 4;  // B col-quad

  const float* __restrict__ Arow =
      X + (size_t)(bm + ar) * F_DIMC + kb * KHALF + akq;
  const float* __restrict__ Bcol =
      W + (size_t)kb * KHALF * M_DIM + bn + bnq;

  float4 pa  = *(const float4*)(Arow);
  float4 pb0 = *(const float4*)(Bcol + (size_t)bk0 * M_DIM);
  float4 pb1 = *(const float4*)(Bcol + (size_t)bk1 * M_DIM);

  float acc[2][4] = {};

  As[0][akq + 0][ar] = pa.x;
  As[0][akq + 1][ar] = pa.y;
  As[0][akq + 2][ar] = pa.z;
  As[0][akq + 3][ar] = pa.w;
  *(float4*)&Bs[0][bk0][bnq] = pb0;
  *(float4*)&Bs[0][bk1][bnq] = pb1;
  __syncthreads();

  for (int it = 0; it < NT2; ++it) {
    const int cur = it & 1;
    if (it + 1 < NT2) {
      const int k0 = (it + 1) * 32;
      pa  = *(const float4*)(Arow + k0);
      pb0 = *(const float4*)(Bcol + (size_t)(k0 + bk0) * M_DIM);
      pb1 = *(const float4*)(Bcol + (size_t)(k0 + bk1) * M_DIM);
    }
#pragma unroll
    for (int kk = 0; kk < 32; ++kk) {
      float2 av = *(const float2*)&As[cur][kk][ty * 2];
      float4 bv = *(const float4*)&Bs[cur][kk][tx * 4];
      acc[0][0] += av.x * bv.x;
      acc[0][1] += av.x * bv.y;
      acc[0][2] += av.x * bv.z;
      acc[0][3] += av.x * bv.w;
      acc[1][0] += av.y * bv.x;
      acc[1][1] += av.y * bv.y;
      acc[1][2] += av.y * bv.z;
      acc[1][3] += av.y * bv.w;
    }
    if (it + 1 < NT2) {
      const int nxt = cur ^ 1;
      As[nxt][akq + 0][ar] = pa.x;
      As[nxt][akq + 1][ar] = pa.y;
      As[nxt][akq + 2][ar] = pa.z;
      As[nxt][akq + 3][ar] = pa.w;
      *(float4*)&Bs[nxt][bk0][bnq] = pb0;
      *(float4*)&Bs[nxt][bk1][bnq] = pb1;
    }
    __syncthreads();
  }

  float* __restrict__ dst = part + (size_t)kb * B_N * M_DIM;
#pragma unroll
  for (int j = 0; j < 2; ++j) {
    float4 o = make_float4(acc[j][0], acc[j][1], acc[j][2], acc[j][3]);
    *(float4*)&dst[(size_t)(bm + ty * 2 + j) * M_DIM + bn + tx * 4] = o;
  }
}

// ---------------------------------------------------------------------------
// Kernel 2: phi row-panels + mu/count. feat = relu(p0 + p1) built in staging.
// grid = (17, C): panels 0..15 -> 32 rows x 512 cols; panel 16 -> mu/count.
// 256 thr. Thread t: rows (t>>6)*8..+8, cols {tc*4..+3} and {256+tc*4..+3}
// (tc = t&63). bv = 2x ds_read_b128 lane-contiguous (conflict-free), av = 2x
// ds_read_b128 wave-uniform (broadcast). Stores: dense 1KB/wave-instr nt
// float4 (native ext_vector_type for the builtin).
// ---------------------------------------------------------------------------
__global__ __launch_bounds__(256, 4) void phi_mu_kernel(
    const float* __restrict__ p0, const float* __restrict__ p1,
    const int* __restrict__ counts, const int* __restrict__ idx,
    float* __restrict__ phi, float* __restrict__ mu,
    float* __restrict__ cnt_out) {
  const int c = blockIdx.y;
  const int n = counts[c];
  const int* __restrict__ id = idx + c * B_N;
  const int t = threadIdx.x;

  if (blockIdx.x == 16) {  // ---- mu / count path ----
    float2 acc = make_float2(0.f, 0.f);
    for (int s = 0; s < n; ++s) {
      const size_t o = (size_t)id[s] * M_DIM + t * 2;
      const float2 q0 = *(const float2*)&p0[o];
      const float2 q1 = *(const float2*)&p1[o];
      acc.x += fmaxf(q0.x + q1.x, 0.f);
      acc.y += fmaxf(q0.y + q1.y, 0.f);
    }
    *(float2*)&mu[(size_t)c * M_DIM + t * 2] = acc;
    if (t == 0) cnt_out[c] = (float)n;
    return;
  }

  // ---- phi row-panel path: rows 32*px..+32, all 512 cols ----
  const int px = (int)blockIdx.x;      // 0..15
  const int tr = t >> 6;               // row group 0..3 (x8 rows)
  const int tc = t & 63;               // col group: cols tc*4 and 256+tc*4

  __shared__ float F[16][M_DIM];

  float acc[8][8] = {};  // [r][q]: q<4 -> col tc*4+q ; q>=4 -> 256+tc*4+q-4

  for (int s0 = 0; s0 < n; s0 += 16) {
    const int chunk  = min(16, n - s0);
    if (s0) __syncthreads();           // protect F before overwrite
    const int nslots = chunk << 7;     // chunk * 128 float4 per row
    for (int v = t; v < nslots; v += 256) {
      const int sl   = v >> 7;
      const int fp   = (v & 127) << 2;
      const size_t o = (size_t)id[s0 + sl] * M_DIM + fp;
      const float4 q0 = *(const float4*)&p0[o];
      const float4 q1 = *(const float4*)&p1[o];
      float4 f;
      f.x = fmaxf(q0.x + q1.x, 0.f);
      f.y = fmaxf(q0.y + q1.y, 0.f);
      f.z = fmaxf(q0.z + q1.z, 0.f);
      f.w = fmaxf(q0.w + q1.w, 0.f);
      *(float4*)&F[sl][fp] = f;
    }
    __syncthreads();
    for (int sl = 0; sl < chunk; ++sl) {
      const float4 a0 = *(const float4*)&F[sl][px * 32 + tr * 8];      // bcast
      const float4 a1 = *(const float4*)&F[sl][px * 32 + tr * 8 + 4];  // bcast
      const float4 b0 = *(const float4*)&F[sl][tc * 4];        // contiguous
      const float4 b1 = *(const float4*)&F[sl][256 + tc * 4];  // contiguous
      const float av[8] = {a0.x, a0.y, a0.z, a0.w, a1.x, a1.y, a1.z, a1.w};
      const float bv[8] = {b0.x, b0.y, b0.z, b0.w, b1.x, b1.y, b1.z, b1.w};
#pragma unroll
      for (int r = 0; r < 8; ++r)
#pragma unroll
        for (int q = 0; q < 8; ++q)
          acc[r][q] += av[r] * bv[q];
    }
  }

  float* __restrict__ out = phi + (size_t)c * M_DIM * M_DIM;
#pragma unroll
  for (int r = 0; r < 8; ++r) {
    const size_t row = (size_t)(px * 32 + tr * 8 + r) * M_DIM;
    const f32x4 o0 = {acc[r][0], acc[r][1], acc[r][2], acc[r][3]};
    const f32x4 o1 = {acc[r][4], acc[r][5], acc[r][6], acc[r][7]};
    __builtin_nontemporal_store(o0, (f32x4*)&out[row + tc * 4]);
    __builtin_nontemporal_store(o1, (f32x4*)&out[row + 256 + tc * 4]);
  }
}

// ---------------------------------------------------------------------------
extern "C" void kernel_launch(void* const* d_in, const int* in_sizes, int n_in,
                              void* d_out, int out_size, void* d_ws,
                              size_t ws_size, hipStream_t stream) {
  const float* X      = (const float*)d_in[0];
  const float* W      = (const float*)d_in[1];
  const int*   labels = (const int*)d_in[2];

  float* out = (float*)d_out;
  float* phi = out;                                // C*M*M
  float* mu  = out + (size_t)C_N * M_DIM * M_DIM;  // C*M
  float* cnt = mu + (size_t)C_N * M_DIM;           // C

  float* part   = (float*)d_ws;                    // 2 x B*M fp32 = 4 MB
  int*   counts = (int*)((char*)d_ws + (size_t)2 * B_N * M_DIM * sizeof(float));
  int*   idx    = counts + 128;                    // C*B ints

  hipLaunchKernelGGL(gemm_index_kernel, dim3(NGEMM + NIDX), dim3(256), 0,
                     stream, X, W, labels, part, counts, idx);
  hipLaunchKernelGGL(phi_mu_kernel, dim3(17, C_N), dim3(256), 0, stream,
                     part, part + (size_t)B_N * M_DIM, counts, idx,
                     phi, mu, cnt);
}